// Round 18
// baseline (428.878 us; speedup 1.0000x reference)
//
#include <hip/hip_runtime.h>
#include <hip/hip_bf16.h>

#define INF 128
#define HF 64

#define HS 64              // edge slices
// hist partition: packed ushort bins, 2 nodes per u32
#define HR_H 32768         // nodes per hist range (16384 u32 = 64 KB LDS)
#define NR_H 4             // ceil(100000/32768)
// fillp partition: int bins
#define HR_F 16384         // nodes per fillp range (64 KB LDS)
#define NR_F 7             // ceil(100000/16384)

typedef __attribute__((ext_vector_type(8))) short short8v;   // 8 bf16 (4 VGPRs)
typedef __attribute__((ext_vector_type(4))) float f32x4;

__device__ inline unsigned short bf16r(float f) {
    __hip_bfloat16 h = __float2bfloat16(f);
    return *reinterpret_cast<unsigned short*>(&h);
}

// ---------------- fused src+dst histograms: packed ushort LDS bins ----------------
__global__ __launch_bounds__(512) void hist2_kernel(const int* __restrict__ src,
        const int* __restrict__ dst, unsigned* __restrict__ Hs,
        unsigned* __restrict__ Hd, int E, int SL) {
    __shared__ unsigned h[HR_H / 2];
    const int t = threadIdx.x;
    const int which = blockIdx.x >> 8;          // 0: src, 1: dst
    const int rs = blockIdx.x & 255;
    const int r = rs >> 6;
    const int s = rs & 63;
    const int base = r * HR_H;
    const int* key = which ? dst : src;
    unsigned* H = which ? Hd : Hs;
    for (int i = t; i < HR_H / 2; i += 512) h[i] = 0u;
    __syncthreads();
    const int e0 = s * SL;
    const int e1 = min(e0 + SL, E);
    const int nq = (e1 > e0) ? (e1 - e0) >> 2 : 0;
    for (int g = t; g < nq; g += 512) {
        int4 k4 = *reinterpret_cast<const int4*>(key + e0 + 4 * g);
        unsigned v0 = (unsigned)(k4.x - base);
        unsigned v1 = (unsigned)(k4.y - base);
        unsigned v2 = (unsigned)(k4.z - base);
        unsigned v3 = (unsigned)(k4.w - base);
        if (v0 < HR_H) atomicAdd(&h[v0 >> 1], 1u << ((v0 & 1) << 4));
        if (v1 < HR_H) atomicAdd(&h[v1 >> 1], 1u << ((v1 & 1) << 4));
        if (v2 < HR_H) atomicAdd(&h[v2 >> 1], 1u << ((v2 & 1) << 4));
        if (v3 < HR_H) atomicAdd(&h[v3 >> 1], 1u << ((v3 & 1) << 4));
    }
    for (int e = e0 + 4 * nq + t; e < e1; e += 512) {
        unsigned v = (unsigned)(key[e] - base);
        if (v < HR_H) atomicAdd(&h[v >> 1], 1u << ((v & 1) << 4));
    }
    __syncthreads();
    unsigned* Hp = H + (size_t)(r * HS + s) * (HR_H / 2);
    for (int i = t; i < HR_H / 2; i += 512) Hp[i] = h[i];
}

// ---------------- prep: word-parallel (2 nodes/thread) ----------------
__global__ __launch_bounds__(256) void prep_kernel(const unsigned* __restrict__ Hs,
        unsigned* __restrict__ Hd, int* __restrict__ cnt_dst,
        float* __restrict__ nout, float* __restrict__ nin, int N) {
    int w = blockIdx.x * 256 + threadIdx.x;     // word = node pair (2w, 2w+1)
    int NW = (N + 1) >> 1;
    if (w >= NW) return;
    int r  = w >> 14;                           // 16384 words per range
    int lw = w & 16383;
    const unsigned* ps = Hs + (size_t)r * HS * (HR_H / 2) + lw;
    unsigned s_lo = 0, s_hi = 0;
    #pragma unroll 8
    for (int s = 0; s < HS; ++s) {
        unsigned v = ps[(size_t)s * (HR_H / 2)];
        s_lo += v & 0xffffu;
        s_hi += v >> 16;
    }
    unsigned* pd = Hd + (size_t)r * HS * (HR_H / 2) + lw;
    unsigned run_lo = 0, run_hi = 0;
    for (int s = 0; s < HS; ++s) {
        unsigned v = pd[(size_t)s * (HR_H / 2)];
        pd[(size_t)s * (HR_H / 2)] = run_lo | (run_hi << 16);
        run_lo += v & 0xffffu;
        run_hi += v >> 16;
    }
    int n0 = 2 * w, n1 = 2 * w + 1;
    cnt_dst[n0] = (int)run_lo;
    nout[n0] = s_lo ? rsqrtf((float)s_lo) : 0.f;
    nin[n0]  = run_lo ? rsqrtf((float)run_lo) : 0.f;
    if (n1 < N) {
        cnt_dst[n1] = (int)run_hi;
        nout[n1] = s_hi ? rsqrtf((float)s_hi) : 0.f;
        nin[n1]  = run_hi ? rsqrtf((float)run_hi) : 0.f;
    }
}

// ---------------- parallel 3-phase exclusive scan: cnt_dst -> rowstart ----------------
__global__ __launch_bounds__(256) void scan_blocks_kernel(const int* __restrict__ deg,
        int* __restrict__ rowstart, int* __restrict__ bsum, int N) {
    __shared__ int sh[256];
    const int b = blockIdx.x, t = threadIdx.x;
    const int base = b * 1024 + t * 4;
    int v0 = (base + 0 < N) ? deg[base + 0] : 0;
    int v1 = (base + 1 < N) ? deg[base + 1] : 0;
    int v2 = (base + 2 < N) ? deg[base + 2] : 0;
    int v3 = (base + 3 < N) ? deg[base + 3] : 0;
    sh[t] = v0 + v1 + v2 + v3;
    __syncthreads();
    for (int off = 1; off < 256; off <<= 1) {
        int x = (t >= off) ? sh[t - off] : 0;
        __syncthreads();
        sh[t] += x;
        __syncthreads();
    }
    if (t == 255) bsum[b] = sh[255];
    int run = (t == 0) ? 0 : sh[t - 1];
    if (base + 0 < N) { rowstart[base + 0] = run; run += v0; }
    if (base + 1 < N) { rowstart[base + 1] = run; run += v1; }
    if (base + 2 < N) { rowstart[base + 2] = run; run += v2; }
    if (base + 3 < N) { rowstart[base + 3] = run; }
}

__global__ __launch_bounds__(1024) void scan_bsums_kernel(int* __restrict__ bsum, int NB) {
    __shared__ int sh[1024];
    const int t = threadIdx.x;
    int v = (t < NB) ? bsum[t] : 0;
    sh[t] = v;
    __syncthreads();
    for (int off = 1; off < 1024; off <<= 1) {
        int x = (t >= off) ? sh[t - off] : 0;
        __syncthreads();
        sh[t] += x;
        __syncthreads();
    }
    if (t < NB) bsum[t] = sh[t] - v;   // exclusive
}

__global__ __launch_bounds__(256) void scan_add_kernel(int* __restrict__ rowstart,
        const int* __restrict__ bsum, int N) {
    const int b = blockIdx.x;
    if (b == 0) return;
    const int t = threadIdx.x;
    const int off = bsum[b];
    const int base = b * 1024 + t * 4;
    if (base + 0 < N) rowstart[base + 0] += off;
    if (base + 1 < N) rowstart[base + 1] += off;
    if (base + 2 < N) rowstart[base + 2] += off;
    if (base + 3 < N) rowstart[base + 3] += off;
}

// ---------------- fillp: LDS counting-sort scatter (no global atomics) ----------------
__global__ __launch_bounds__(512) void fillp_kernel(const int* __restrict__ src,
        const int* __restrict__ dst, const int* __restrict__ rowstart,
        const unsigned* __restrict__ Hd, int* __restrict__ esrc, int E, int N, int SL) {
    __shared__ int h[HR_F];
    const int t = threadIdx.x;
    const int r = blockIdx.x >> 6;      // 0..NR_F-1
    const int s = blockIdx.x & 63;
    const int base = r * HR_F;
    const int rh   = r >> 1;            // hist range
    const int off0 = (r & 1) * HR_F;    // node offset within hist range
    const unsigned* Hp = Hd + (size_t)(rh * HS + s) * (HR_H / 2);
    for (int i = t; i < HR_F; i += 512) {
        int n = base + i;
        int seed = 0;
        if (n < N) {
            int l = off0 + i;
            unsigned v = Hp[l >> 1];
            unsigned pre = (l & 1) ? (v >> 16) : (v & 0xffffu);
            seed = rowstart[n] + (int)pre;
        }
        h[i] = seed;
    }
    __syncthreads();
    const int e0 = s * SL;
    const int e1 = min(e0 + SL, E);
    const int nq = (e1 > e0) ? (e1 - e0) >> 2 : 0;
    for (int g = t; g < nq; g += 512) {
        const int e = e0 + 4 * g;
        int4 d4 = *reinterpret_cast<const int4*>(dst + e);
        int4 s4 = *reinterpret_cast<const int4*>(src + e);
        unsigned v0 = (unsigned)(d4.x - base);
        unsigned v1 = (unsigned)(d4.y - base);
        unsigned v2 = (unsigned)(d4.z - base);
        unsigned v3 = (unsigned)(d4.w - base);
        if (v0 < HR_F) esrc[atomicAdd(&h[v0], 1)] = s4.x;
        if (v1 < HR_F) esrc[atomicAdd(&h[v1], 1)] = s4.y;
        if (v2 < HR_F) esrc[atomicAdd(&h[v2], 1)] = s4.z;
        if (v3 < HR_F) esrc[atomicAdd(&h[v3], 1)] = s4.w;
    }
    for (int e = e0 + 4 * nq + t; e < e1; e += 512) {
        unsigned v = (unsigned)(dst[e] - base);
        if (v < HR_F) esrc[atomicAdd(&h[v], 1)] = src[e];
    }
}

// ---------------- W transpose to bf16: WT[o][k] = bf16(W[k][o]) ----------------
__global__ __launch_bounds__(256) void wt_kernel(const float* __restrict__ W1,
        const float* __restrict__ W2, unsigned short* __restrict__ W1T,
        unsigned short* __restrict__ W2T) {
    int i = blockIdx.x * 256 + threadIdx.x;
    if (i < 128 * 128) {
        int o = i >> 7, k = i & 127;
        W1T[i] = bf16r(W1[k * 128 + o]);
    }
    if (i < 64 * 128) {
        int o = i >> 7, k = i & 127;
        W2T[i] = bf16r(W2[k * 64 + o]);
    }
}

// ---------------- MFMA GEMM -> SLICE-MAJOR bf16 output ----------------
// H layout: [slice = col-tile n][node][16]; slice table = N*32B (L2-scale per XCD)
template<int OUT, bool BF16IN>
__global__ __launch_bounds__(256) void gemm_mfma_kernel(const void* __restrict__ Xv,
        const float* __restrict__ rowscale,            // may be null (fp32 path only)
        const unsigned short* __restrict__ WT,         // bf16 [OUT][128]
        unsigned short* __restrict__ H, int N) {
    constexpr int K   = 128;
    constexpr int LDP = K + 8;
    constexpr int NT  = OUT / 16;

    __shared__ unsigned short sX[64 * LDP];
    __shared__ unsigned short sWT[OUT * LDP];

    const int tid  = threadIdx.x;
    const int row0 = blockIdx.x * 64;

    if constexpr (BF16IN) {
        const unsigned short* X = (const unsigned short*)Xv;
        for (int i = tid; i < 64 * 16; i += 256) {
            int rr = i >> 4, kq = i & 15;
            int gr = row0 + rr;
            int4 u = make_int4(0, 0, 0, 0);
            if (gr < N)
                u = *reinterpret_cast<const int4*>(&X[(size_t)gr * K + kq * 8]);
            *reinterpret_cast<int4*>(&sX[rr * LDP + kq * 8]) = u;
        }
    } else {
        const float* X = (const float*)Xv;
        for (int i = tid; i < 64 * 32; i += 256) {
            int rr = i >> 5, kq = i & 31;
            int gr = row0 + rr;
            float4 v = make_float4(0.f, 0.f, 0.f, 0.f);
            if (gr < N) {
                v = reinterpret_cast<const float4*>(X)[(size_t)gr * 32 + kq];
                if (rowscale) { float s = rowscale[gr]; v.x *= s; v.y *= s; v.z *= s; v.w *= s; }
            }
            ushort4 u;
            u.x = bf16r(v.x); u.y = bf16r(v.y); u.z = bf16r(v.z); u.w = bf16r(v.w);
            *reinterpret_cast<ushort4*>(&sX[rr * LDP + kq * 4]) = u;
        }
    }
    for (int i = tid; i < OUT * (K / 8); i += 256) {
        int o = i >> 4, kq = i & 15;
        *reinterpret_cast<int4*>(&sWT[o * LDP + kq * 8]) =
            *reinterpret_cast<const int4*>(&WT[o * K + kq * 8]);
    }
    __syncthreads();

    const int w  = tid >> 6;
    const int l  = tid & 63;
    const int lr = l & 15;
    const int lk = (l >> 4) * 8;

    f32x4 acc[NT];
    #pragma unroll
    for (int n = 0; n < NT; ++n) acc[n] = (f32x4){0.f, 0.f, 0.f, 0.f};

    #pragma unroll
    for (int k0 = 0; k0 < K; k0 += 32) {
        short8v a = *reinterpret_cast<const short8v*>(&sX[(w * 16 + lr) * LDP + k0 + lk]);
        #pragma unroll
        for (int n = 0; n < NT; ++n) {
            short8v b = *reinterpret_cast<const short8v*>(&sWT[(n * 16 + lr) * LDP + k0 + lk]);
            acc[n] = __builtin_amdgcn_mfma_f32_16x16x32_bf16(a, b, acc[n], 0, 0, 0);
        }
    }

    const int rbase = row0 + w * 16 + (l >> 4) * 4;
    #pragma unroll
    for (int j = 0; j < 4; ++j) {
        int gr = rbase + j;
        if (gr < N) {
            #pragma unroll
            for (int n = 0; n < NT; ++n)
                H[((size_t)n * N + gr) * 16 + lr] = bf16r(acc[n][j]);
        }
    }
}

// ---------------- XCD-affine sliced gather-aggregate ----------------
// slice = bid % NSL rides the round-robin block->XCD mapping; slice table N*32B
// wave: 8 groups x 8 lanes (2 feats/lane); shfl_xor group-reduce; g==0 writes.
// NOTE: every __shfl executes under a WAVE-UNIFORM branch (ds_bpermute returns 0
// from EXEC-disabled source lanes — divergent-source shfl corrupted round 16).
template<bool L1>
__global__ __launch_bounds__(256) void aggs_kernel(const __hip_bfloat162* __restrict__ Hs,
        const int* __restrict__ esrc, const int* __restrict__ rowstart,
        const int* __restrict__ cnt, const float* __restrict__ nin,
        const float* __restrict__ bias, const float* __restrict__ nout,
        void* __restrict__ outv, int N) {
    constexpr int NSL = L1 ? 8 : 4;
    const int bid = blockIdx.x;
    const int slice = bid & (NSL - 1);
    const int chunk = bid / NSL;
    const int wv = threadIdx.x >> 6;
    const int l  = threadIdx.x & 63;
    const int g  = l >> 3;
    const int f  = l & 7;
    const __hip_bfloat162* T = Hs + (size_t)slice * N * 8;
    const int colp = slice * 8 + f;            // output float2/bf162 pair index
    const int node0 = (chunk * 4 + wv) * 8;    // 8 nodes per wave
    for (int ni = 0; ni < 8; ++ni) {
        int wid = node0 + ni;
        if (wid >= N) return;
        int beg = rowstart[wid];
        int cw  = cnt[wid];
        float ax = 0.f, ay = 0.f, bx = 0.f, by = 0.f;
        for (int j0 = 0; j0 < cw; j0 += 64) {
            int m = min(64, cw - j0);
            int idx = (l < m) ? esrc[beg + j0 + l] : 0;
            int jj = 0;
            for (; jj + 16 <= m; jj += 16) {           // uniform branch
                int s0 = __shfl(idx, jj + g);
                int s1 = __shfl(idx, jj + 8 + g);
                float2 v0 = __bfloat1622float2(T[(size_t)s0 * 8 + f]);
                float2 v1 = __bfloat1622float2(T[(size_t)s1 * 8 + f]);
                ax += v0.x; ay += v0.y; bx += v1.x; by += v1.y;
            }
            if (jj + 8 <= m) {                          // uniform branch
                int s0 = __shfl(idx, jj + g);
                float2 v0 = __bfloat1622float2(T[(size_t)s0 * 8 + f]);
                ax += v0.x; ay += v0.y;
                jj += 8;
            }
            int rem = m - jj;
            if (rem > 0) {                              // uniform branch; shfl by ALL lanes
                int s0 = __shfl(idx, jj + (g < rem ? g : 0));
                if (g < rem) {                          // predicate only the accumulate
                    float2 v0 = __bfloat1622float2(T[(size_t)s0 * 8 + f]);
                    ax += v0.x; ay += v0.y;
                }
            }
        }
        ax += bx; ay += by;
        ax += __shfl_xor(ax, 8);  ay += __shfl_xor(ay, 8);
        ax += __shfl_xor(ax, 16); ay += __shfl_xor(ay, 16);
        ax += __shfl_xor(ax, 32); ay += __shfl_xor(ay, 32);
        if (g == 0) {
            float s = nin[wid];
            float2 b = ((const float2*)bias)[colp];
            float r0 = fmaxf(fmaf(ax, s, b.x), 0.f);
            float r1 = fmaxf(fmaf(ay, s, b.y), 0.f);
            if constexpr (L1) {
                float t = nout[wid];
                r0 *= t; r1 *= t;
                __hip_bfloat162 p = __float22bfloat162_rn(make_float2(r0, r1));
                ((unsigned*)outv)[(size_t)wid * 64 + colp] = *reinterpret_cast<unsigned*>(&p);
            } else {
                ((float2*)outv)[(size_t)wid * 32 + colp] = make_float2(r0, r1);
            }
        }
    }
}

// ---------------- launch ----------------

extern "C" void kernel_launch(void* const* d_in, const int* in_sizes, int n_in,
                              void* d_out, int out_size, void* d_ws, size_t ws_size,
                              hipStream_t stream) {
    const float* x  = (const float*)d_in[0];
    const float* W1 = (const float*)d_in[1];
    const float* b1 = (const float*)d_in[2];
    const float* W2 = (const float*)d_in[3];
    const float* b2 = (const float*)d_in[4];
    const int*   src = (const int*)d_in[5];
    const int*   dst = (const int*)d_in[6];

    const int N = in_sizes[0] / INF;   // 100000
    const int E = in_sizes[5];         // 1600000

    char* ws = (char*)d_ws;
    const size_t padN    = (((size_t)N * 4 + 255) / 256) * 256;
    const size_t padE    = (((size_t)E * 4 + 255) / 256) * 256;
    const size_t padAbf  = (((size_t)N * INF * 2 + 255) / 256) * 256;   // 25.6 MB
    const size_t padWT   = 49152;

    float* out = (float*)d_out;

    int*   cnt_dst  = (int*)  (ws);
    int*   rowstart = (int*)  (ws + padN);
    float* nout     = (float*)(ws + 2 * padN);
    float* nin      = (float*)(ws + 3 * padN);
    int*   bsum     = (int*)  (ws + 4 * padN);
    unsigned short* W1T = (unsigned short*)(ws + 5 * padN);
    unsigned short* W2T = (unsigned short*)(ws + 5 * padN + 32768);
    int*   esrc     = (int*)  (ws + 5 * padN + padWT);
    char*  regionA  = ws + 5 * padN + padWT + padE;              // Hpart_src, then Abf
    unsigned short* Bbf = (unsigned short*)(regionA + padAbf);   // bf16 N x 128 (row-major)
    unsigned* Hpart_dst = (unsigned*)(regionA + padAbf + padAbf);

    unsigned* Hpart_src = (unsigned*)regionA;   // dead after prep; gemm1 reuses regionA
    unsigned short* Abf = (unsigned short*)regionA;              // slice-major h tables

    const int NB = (N + 1023) / 1024;
    const int NW = (N + 1) >> 1;
    const int SL = ((((E + HS - 1) / HS) + 3) / 4) * 4;          // edges/slice, mult of 4

    // W transposes (tiny)
    wt_kernel<<<64, 256, 0, stream>>>(W1, W2, W1T, W2T);

    // fused src+dst histograms (packed ushort bins, zero global atomics)
    hist2_kernel<<<2 * NR_H * HS, 512, 0, stream>>>(src, dst, Hpart_src, Hpart_dst, E, SL);

    // merge src partials -> nout; prefix dst partials -> cnt_dst, nin
    prep_kernel<<<(NW + 255) / 256, 256, 0, stream>>>(Hpart_src, Hpart_dst,
                                                      cnt_dst, nout, nin, N);

    // rowstart = exclusive scan of cnt_dst
    scan_blocks_kernel<<<NB, 256, 0, stream>>>(cnt_dst, rowstart, bsum, N);
    scan_bsums_kernel<<<1, 1024, 0, stream>>>(bsum, NB);
    scan_add_kernel<<<NB, 256, 0, stream>>>(rowstart, bsum, N);

    // dst-sorted edge fill via LDS counting sort
    fillp_kernel<<<NR_F * HS, 512, 0, stream>>>(src, dst, rowstart, Hpart_dst, esrc, E, N, SL);

    const int GB = (N + 63) / 64;
    const int CH = (N + 31) / 32;     // node chunks (4 waves x 8 nodes per block)

    // layer 1: Abf[slice][node][16] = bf16((x*nout) @ W1) ; Bbf = bf16(post(agg))
    gemm_mfma_kernel<128, false><<<GB, 256, 0, stream>>>(x, nout, W1T, Abf, N);
    aggs_kernel<true><<<CH * 8, 256, 0, stream>>>(
        (const __hip_bfloat162*)Abf, esrc, rowstart, cnt_dst, nin, b1, nout,
        (void*)Bbf, N);

    // layer 2: Abf[slice][node][16] = bf16(Bbf @ W2) ; out = post(agg) fp32
    gemm_mfma_kernel<64, true><<<GB, 256, 0, stream>>>(Bbf, nullptr, W2T, Abf, N);
    aggs_kernel<false><<<CH * 4, 256, 0, stream>>>(
        (const __hip_bfloat162*)Abf, esrc, rowstart, cnt_dst, nin, b2, nullptr,
        (void*)out, N);
}

// Round 19
// 227.096 us; speedup vs baseline: 1.8885x; 1.8885x over previous
//
#include <hip/hip_runtime.h>
#include <hip/hip_bf16.h>

#define INF 128
#define HF 64

#define HS 64              // edge slices
// hist partition: packed ushort bins, 2 nodes per u32
#define HR_H 32768         // nodes per hist range (16384 u32 = 64 KB LDS)
#define NR_H 4             // ceil(100000/32768)
// fillp partition: int bins
#define HR_F 16384         // nodes per fillp range (64 KB LDS)
#define NR_F 7             // ceil(100000/16384)

typedef __attribute__((ext_vector_type(8))) short short8v;   // 8 bf16 (4 VGPRs)
typedef __attribute__((ext_vector_type(4))) float f32x4;

__device__ inline unsigned short bf16r(float f) {
    __hip_bfloat16 h = __float2bfloat16(f);
    return *reinterpret_cast<unsigned short*>(&h);
}

// ---------------- fused src+dst histograms: packed ushort LDS bins ----------------
__global__ __launch_bounds__(512) void hist2_kernel(const int* __restrict__ src,
        const int* __restrict__ dst, unsigned* __restrict__ Hs,
        unsigned* __restrict__ Hd, int E, int SL) {
    __shared__ unsigned h[HR_H / 2];
    const int t = threadIdx.x;
    const int which = blockIdx.x >> 8;          // 0: src, 1: dst
    const int rs = blockIdx.x & 255;
    const int r = rs >> 6;
    const int s = rs & 63;
    const int base = r * HR_H;
    const int* key = which ? dst : src;
    unsigned* H = which ? Hd : Hs;
    for (int i = t; i < HR_H / 2; i += 512) h[i] = 0u;
    __syncthreads();
    const int e0 = s * SL;
    const int e1 = min(e0 + SL, E);
    const int nq = (e1 > e0) ? (e1 - e0) >> 2 : 0;
    for (int g = t; g < nq; g += 512) {
        int4 k4 = *reinterpret_cast<const int4*>(key + e0 + 4 * g);
        unsigned v0 = (unsigned)(k4.x - base);
        unsigned v1 = (unsigned)(k4.y - base);
        unsigned v2 = (unsigned)(k4.z - base);
        unsigned v3 = (unsigned)(k4.w - base);
        if (v0 < HR_H) atomicAdd(&h[v0 >> 1], 1u << ((v0 & 1) << 4));
        if (v1 < HR_H) atomicAdd(&h[v1 >> 1], 1u << ((v1 & 1) << 4));
        if (v2 < HR_H) atomicAdd(&h[v2 >> 1], 1u << ((v2 & 1) << 4));
        if (v3 < HR_H) atomicAdd(&h[v3 >> 1], 1u << ((v3 & 1) << 4));
    }
    for (int e = e0 + 4 * nq + t; e < e1; e += 512) {
        unsigned v = (unsigned)(key[e] - base);
        if (v < HR_H) atomicAdd(&h[v >> 1], 1u << ((v & 1) << 4));
    }
    __syncthreads();
    unsigned* Hp = H + (size_t)(r * HS + s) * (HR_H / 2);
    for (int i = t; i < HR_H / 2; i += 512) Hp[i] = h[i];
}

// ---------------- prep: word-parallel (2 nodes/thread) ----------------
__global__ __launch_bounds__(256) void prep_kernel(const unsigned* __restrict__ Hs,
        unsigned* __restrict__ Hd, int* __restrict__ cnt_dst,
        float* __restrict__ nout, float* __restrict__ nin, int N) {
    int w = blockIdx.x * 256 + threadIdx.x;     // word = node pair (2w, 2w+1)
    int NW = (N + 1) >> 1;
    if (w >= NW) return;
    int r  = w >> 14;                           // 16384 words per range
    int lw = w & 16383;
    const unsigned* ps = Hs + (size_t)r * HS * (HR_H / 2) + lw;
    unsigned s_lo = 0, s_hi = 0;
    #pragma unroll 8
    for (int s = 0; s < HS; ++s) {
        unsigned v = ps[(size_t)s * (HR_H / 2)];
        s_lo += v & 0xffffu;
        s_hi += v >> 16;
    }
    unsigned* pd = Hd + (size_t)r * HS * (HR_H / 2) + lw;
    unsigned run_lo = 0, run_hi = 0;
    for (int s = 0; s < HS; ++s) {
        unsigned v = pd[(size_t)s * (HR_H / 2)];
        pd[(size_t)s * (HR_H / 2)] = run_lo | (run_hi << 16);
        run_lo += v & 0xffffu;
        run_hi += v >> 16;
    }
    int n0 = 2 * w, n1 = 2 * w + 1;
    cnt_dst[n0] = (int)run_lo;
    nout[n0] = s_lo ? rsqrtf((float)s_lo) : 0.f;
    nin[n0]  = run_lo ? rsqrtf((float)run_lo) : 0.f;
    if (n1 < N) {
        cnt_dst[n1] = (int)run_hi;
        nout[n1] = s_hi ? rsqrtf((float)s_hi) : 0.f;
        nin[n1]  = run_hi ? rsqrtf((float)run_hi) : 0.f;
    }
}

// ---------------- parallel 3-phase exclusive scan: cnt_dst -> rowstart ----------------
__global__ __launch_bounds__(256) void scan_blocks_kernel(const int* __restrict__ deg,
        int* __restrict__ rowstart, int* __restrict__ bsum, int N) {
    __shared__ int sh[256];
    const int b = blockIdx.x, t = threadIdx.x;
    const int base = b * 1024 + t * 4;
    int v0 = (base + 0 < N) ? deg[base + 0] : 0;
    int v1 = (base + 1 < N) ? deg[base + 1] : 0;
    int v2 = (base + 2 < N) ? deg[base + 2] : 0;
    int v3 = (base + 3 < N) ? deg[base + 3] : 0;
    sh[t] = v0 + v1 + v2 + v3;
    __syncthreads();
    for (int off = 1; off < 256; off <<= 1) {
        int x = (t >= off) ? sh[t - off] : 0;
        __syncthreads();
        sh[t] += x;
        __syncthreads();
    }
    if (t == 255) bsum[b] = sh[255];
    int run = (t == 0) ? 0 : sh[t - 1];
    if (base + 0 < N) { rowstart[base + 0] = run; run += v0; }
    if (base + 1 < N) { rowstart[base + 1] = run; run += v1; }
    if (base + 2 < N) { rowstart[base + 2] = run; run += v2; }
    if (base + 3 < N) { rowstart[base + 3] = run; }
}

__global__ __launch_bounds__(1024) void scan_bsums_kernel(int* __restrict__ bsum, int NB) {
    __shared__ int sh[1024];
    const int t = threadIdx.x;
    int v = (t < NB) ? bsum[t] : 0;
    sh[t] = v;
    __syncthreads();
    for (int off = 1; off < 1024; off <<= 1) {
        int x = (t >= off) ? sh[t - off] : 0;
        __syncthreads();
        sh[t] += x;
        __syncthreads();
    }
    if (t < NB) bsum[t] = sh[t] - v;   // exclusive
}

__global__ __launch_bounds__(256) void scan_add_kernel(int* __restrict__ rowstart,
        const int* __restrict__ bsum, int N) {
    const int b = blockIdx.x;
    if (b == 0) return;
    const int t = threadIdx.x;
    const int off = bsum[b];
    const int base = b * 1024 + t * 4;
    if (base + 0 < N) rowstart[base + 0] += off;
    if (base + 1 < N) rowstart[base + 1] += off;
    if (base + 2 < N) rowstart[base + 2] += off;
    if (base + 3 < N) rowstart[base + 3] += off;
}

// ---------------- fillp: LDS counting-sort scatter (no global atomics) ----------------
__global__ __launch_bounds__(512) void fillp_kernel(const int* __restrict__ src,
        const int* __restrict__ dst, const int* __restrict__ rowstart,
        const unsigned* __restrict__ Hd, int* __restrict__ esrc, int E, int N, int SL) {
    __shared__ int h[HR_F];
    const int t = threadIdx.x;
    const int r = blockIdx.x >> 6;      // 0..NR_F-1
    const int s = blockIdx.x & 63;
    const int base = r * HR_F;
    const int rh   = r >> 1;            // hist range
    const int off0 = (r & 1) * HR_F;    // node offset within hist range
    const unsigned* Hp = Hd + (size_t)(rh * HS + s) * (HR_H / 2);
    for (int i = t; i < HR_F; i += 512) {
        int n = base + i;
        int seed = 0;
        if (n < N) {
            int l = off0 + i;
            unsigned v = Hp[l >> 1];
            unsigned pre = (l & 1) ? (v >> 16) : (v & 0xffffu);
            seed = rowstart[n] + (int)pre;
        }
        h[i] = seed;
    }
    __syncthreads();
    const int e0 = s * SL;
    const int e1 = min(e0 + SL, E);
    const int nq = (e1 > e0) ? (e1 - e0) >> 2 : 0;
    for (int g = t; g < nq; g += 512) {
        const int e = e0 + 4 * g;
        int4 d4 = *reinterpret_cast<const int4*>(dst + e);
        int4 s4 = *reinterpret_cast<const int4*>(src + e);
        unsigned v0 = (unsigned)(d4.x - base);
        unsigned v1 = (unsigned)(d4.y - base);
        unsigned v2 = (unsigned)(d4.z - base);
        unsigned v3 = (unsigned)(d4.w - base);
        if (v0 < HR_F) esrc[atomicAdd(&h[v0], 1)] = s4.x;
        if (v1 < HR_F) esrc[atomicAdd(&h[v1], 1)] = s4.y;
        if (v2 < HR_F) esrc[atomicAdd(&h[v2], 1)] = s4.z;
        if (v3 < HR_F) esrc[atomicAdd(&h[v3], 1)] = s4.w;
    }
    for (int e = e0 + 4 * nq + t; e < e1; e += 512) {
        unsigned v = (unsigned)(dst[e] - base);
        if (v < HR_F) esrc[atomicAdd(&h[v], 1)] = src[e];
    }
}

// ---------------- W transpose to bf16: WT[o][k] = bf16(W[k][o]) ----------------
__global__ __launch_bounds__(256) void wt_kernel(const float* __restrict__ W1,
        const float* __restrict__ W2, unsigned short* __restrict__ W1T,
        unsigned short* __restrict__ W2T) {
    int i = blockIdx.x * 256 + threadIdx.x;
    if (i < 128 * 128) {
        int o = i >> 7, k = i & 127;
        W1T[i] = bf16r(W1[k * 128 + o]);
    }
    if (i < 64 * 128) {
        int o = i >> 7, k = i & 127;
        W2T[i] = bf16r(W2[k * 64 + o]);
    }
}

// ---------------- MFMA GEMM: H[N,OUT] = bf16( (X*rowscale) @ W ), bf16 out ----------------
template<int OUT, bool BF16IN>
__global__ __launch_bounds__(256) void gemm_mfma_kernel(const void* __restrict__ Xv,
        const float* __restrict__ rowscale,            // may be null (fp32 path only)
        const unsigned short* __restrict__ WT,         // bf16 [OUT][128]
        unsigned short* __restrict__ H, int N) {
    constexpr int K   = 128;
    constexpr int LDP = K + 8;
    constexpr int NT  = OUT / 16;

    __shared__ unsigned short sX[64 * LDP];
    __shared__ unsigned short sWT[OUT * LDP];

    const int tid  = threadIdx.x;
    const int row0 = blockIdx.x * 64;

    if constexpr (BF16IN) {
        const unsigned short* X = (const unsigned short*)Xv;
        for (int i = tid; i < 64 * 16; i += 256) {
            int rr = i >> 4, kq = i & 15;
            int gr = row0 + rr;
            int4 u = make_int4(0, 0, 0, 0);
            if (gr < N)
                u = *reinterpret_cast<const int4*>(&X[(size_t)gr * K + kq * 8]);
            *reinterpret_cast<int4*>(&sX[rr * LDP + kq * 8]) = u;
        }
    } else {
        const float* X = (const float*)Xv;
        for (int i = tid; i < 64 * 32; i += 256) {
            int rr = i >> 5, kq = i & 31;
            int gr = row0 + rr;
            float4 v = make_float4(0.f, 0.f, 0.f, 0.f);
            if (gr < N) {
                v = reinterpret_cast<const float4*>(X)[(size_t)gr * 32 + kq];
                if (rowscale) { float s = rowscale[gr]; v.x *= s; v.y *= s; v.z *= s; v.w *= s; }
            }
            ushort4 u;
            u.x = bf16r(v.x); u.y = bf16r(v.y); u.z = bf16r(v.z); u.w = bf16r(v.w);
            *reinterpret_cast<ushort4*>(&sX[rr * LDP + kq * 4]) = u;
        }
    }
    for (int i = tid; i < OUT * (K / 8); i += 256) {
        int o = i >> 4, kq = i & 15;
        *reinterpret_cast<int4*>(&sWT[o * LDP + kq * 8]) =
            *reinterpret_cast<const int4*>(&WT[o * K + kq * 8]);
    }
    __syncthreads();

    const int w  = tid >> 6;
    const int l  = tid & 63;
    const int lr = l & 15;
    const int lk = (l >> 4) * 8;

    f32x4 acc[NT];
    #pragma unroll
    for (int n = 0; n < NT; ++n) acc[n] = (f32x4){0.f, 0.f, 0.f, 0.f};

    #pragma unroll
    for (int k0 = 0; k0 < K; k0 += 32) {
        short8v a = *reinterpret_cast<const short8v*>(&sX[(w * 16 + lr) * LDP + k0 + lk]);
        #pragma unroll
        for (int n = 0; n < NT; ++n) {
            short8v b = *reinterpret_cast<const short8v*>(&sWT[(n * 16 + lr) * LDP + k0 + lk]);
            acc[n] = __builtin_amdgcn_mfma_f32_16x16x32_bf16(a, b, acc[n], 0, 0, 0);
        }
    }

    const int rbase = row0 + w * 16 + (l >> 4) * 4;
    #pragma unroll
    for (int j = 0; j < 4; ++j) {
        int gr = rbase + j;
        if (gr < N) {
            #pragma unroll
            for (int n = 0; n < NT; ++n)
                H[(size_t)gr * OUT + n * 16 + lr] = bf16r(acc[n][j]);
        }
    }
}

// ---------------- CSR gather-aggregate: shfl-prefetched indices, 8-way MLP ----------------

// layer 1: bf16 in (N x 128), bf16 out (relu(acc*nin+b)*nout)
__global__ __launch_bounds__(256) void agg128_kernel(const __hip_bfloat162* __restrict__ H,
        const int* __restrict__ esrc, const int* __restrict__ rowstart,
        const int* __restrict__ cnt,
        const float* __restrict__ nin, const float* __restrict__ bias,
        const float* __restrict__ nout, unsigned int* __restrict__ outb, int N) {
    int wid  = (blockIdx.x * 256 + threadIdx.x) >> 6;
    int lane = threadIdx.x & 63;
    if (wid >= N) return;
    int beg = rowstart[wid];
    int cw  = cnt[wid];
    float2 a0 = make_float2(0.f, 0.f), a1 = make_float2(0.f, 0.f);
    float2 a2 = make_float2(0.f, 0.f), a3 = make_float2(0.f, 0.f);
    float2 a4 = make_float2(0.f, 0.f), a5 = make_float2(0.f, 0.f);
    float2 a6 = make_float2(0.f, 0.f), a7 = make_float2(0.f, 0.f);
    for (int j0 = 0; j0 < cw; j0 += 64) {
        int m = min(64, cw - j0);
        int idx = (lane < m) ? esrc[beg + j0 + lane] : 0;
        int jj = 0;
        for (; jj + 8 <= m; jj += 8) {
            int s0 = __shfl(idx, jj + 0);
            int s1 = __shfl(idx, jj + 1);
            int s2 = __shfl(idx, jj + 2);
            int s3 = __shfl(idx, jj + 3);
            int s4 = __shfl(idx, jj + 4);
            int s5 = __shfl(idx, jj + 5);
            int s6 = __shfl(idx, jj + 6);
            int s7 = __shfl(idx, jj + 7);
            float2 v0 = __bfloat1622float2(H[(size_t)s0 * 64 + lane]);
            float2 v1 = __bfloat1622float2(H[(size_t)s1 * 64 + lane]);
            float2 v2 = __bfloat1622float2(H[(size_t)s2 * 64 + lane]);
            float2 v3 = __bfloat1622float2(H[(size_t)s3 * 64 + lane]);
            float2 v4 = __bfloat1622float2(H[(size_t)s4 * 64 + lane]);
            float2 v5 = __bfloat1622float2(H[(size_t)s5 * 64 + lane]);
            float2 v6 = __bfloat1622float2(H[(size_t)s6 * 64 + lane]);
            float2 v7 = __bfloat1622float2(H[(size_t)s7 * 64 + lane]);
            a0.x += v0.x; a0.y += v0.y;  a1.x += v1.x; a1.y += v1.y;
            a2.x += v2.x; a2.y += v2.y;  a3.x += v3.x; a3.y += v3.y;
            a4.x += v4.x; a4.y += v4.y;  a5.x += v5.x; a5.y += v5.y;
            a6.x += v6.x; a6.y += v6.y;  a7.x += v7.x; a7.y += v7.y;
        }
        for (; jj < m; ++jj) {
            int s0 = __shfl(idx, jj);
            float2 v0 = __bfloat1622float2(H[(size_t)s0 * 64 + lane]);
            a0.x += v0.x; a0.y += v0.y;
        }
    }
    a0.x += a1.x + a2.x + a3.x + a4.x + a5.x + a6.x + a7.x;
    a0.y += a1.y + a2.y + a3.y + a4.y + a5.y + a6.y + a7.y;
    float s = nin[wid];
    float2 b = ((const float2*)bias)[lane];
    float r0 = fmaxf(fmaf(a0.x, s, b.x), 0.f);
    float r1 = fmaxf(fmaf(a0.y, s, b.y), 0.f);
    float t = nout[wid];
    r0 *= t; r1 *= t;
    __hip_bfloat162 p = __float22bfloat162_rn(make_float2(r0, r1));
    outb[(size_t)wid * 64 + lane] = *reinterpret_cast<unsigned int*>(&p);
}

// layer 2: bf16 in (N x 64), fp32 out
__global__ __launch_bounds__(256) void agg64_kernel(const __hip_bfloat16* __restrict__ H,
        const int* __restrict__ esrc, const int* __restrict__ rowstart,
        const int* __restrict__ cnt,
        const float* __restrict__ nin, const float* __restrict__ bias,
        float* __restrict__ out, int N) {
    int wid  = (blockIdx.x * 256 + threadIdx.x) >> 6;
    int lane = threadIdx.x & 63;
    if (wid >= N) return;
    int beg = rowstart[wid];
    int cw  = cnt[wid];
    float a0 = 0.f, a1 = 0.f, a2 = 0.f, a3 = 0.f;
    float a4 = 0.f, a5 = 0.f, a6 = 0.f, a7 = 0.f;
    for (int j0 = 0; j0 < cw; j0 += 64) {
        int m = min(64, cw - j0);
        int idx = (lane < m) ? esrc[beg + j0 + lane] : 0;
        int jj = 0;
        for (; jj + 8 <= m; jj += 8) {
            int s0 = __shfl(idx, jj + 0);
            int s1 = __shfl(idx, jj + 1);
            int s2 = __shfl(idx, jj + 2);
            int s3 = __shfl(idx, jj + 3);
            int s4 = __shfl(idx, jj + 4);
            int s5 = __shfl(idx, jj + 5);
            int s6 = __shfl(idx, jj + 6);
            int s7 = __shfl(idx, jj + 7);
            a0 += __bfloat162float(H[(size_t)s0 * 64 + lane]);
            a1 += __bfloat162float(H[(size_t)s1 * 64 + lane]);
            a2 += __bfloat162float(H[(size_t)s2 * 64 + lane]);
            a3 += __bfloat162float(H[(size_t)s3 * 64 + lane]);
            a4 += __bfloat162float(H[(size_t)s4 * 64 + lane]);
            a5 += __bfloat162float(H[(size_t)s5 * 64 + lane]);
            a6 += __bfloat162float(H[(size_t)s6 * 64 + lane]);
            a7 += __bfloat162float(H[(size_t)s7 * 64 + lane]);
        }
        for (; jj < m; ++jj) {
            int s0 = __shfl(idx, jj);
            a0 += __bfloat162float(H[(size_t)s0 * 64 + lane]);
        }
    }
    float acc = ((a0 + a1) + (a2 + a3)) + ((a4 + a5) + (a6 + a7));
    float r = fmaxf(fmaf(acc, nin[wid], bias[lane]), 0.f);
    out[(size_t)wid * 64 + lane] = r;
}

// ---------------- launch ----------------

extern "C" void kernel_launch(void* const* d_in, const int* in_sizes, int n_in,
                              void* d_out, int out_size, void* d_ws, size_t ws_size,
                              hipStream_t stream) {
    const float* x  = (const float*)d_in[0];
    const float* W1 = (const float*)d_in[1];
    const float* b1 = (const float*)d_in[2];
    const float* W2 = (const float*)d_in[3];
    const float* b2 = (const float*)d_in[4];
    const int*   src = (const int*)d_in[5];
    const int*   dst = (const int*)d_in[6];

    const int N = in_sizes[0] / INF;   // 100000
    const int E = in_sizes[5];         // 1600000

    char* ws = (char*)d_ws;
    const size_t padN    = (((size_t)N * 4 + 255) / 256) * 256;
    const size_t padE    = (((size_t)E * 4 + 255) / 256) * 256;
    const size_t padAbf  = (((size_t)N * INF * 2 + 255) / 256) * 256;   // 25.6 MB
    const size_t padWT   = 49152;

    float* out = (float*)d_out;

    int*   cnt_dst  = (int*)  (ws);
    int*   rowstart = (int*)  (ws + padN);
    float* nout     = (float*)(ws + 2 * padN);
    float* nin      = (float*)(ws + 3 * padN);
    int*   bsum     = (int*)  (ws + 4 * padN);
    unsigned short* W1T = (unsigned short*)(ws + 5 * padN);
    unsigned short* W2T = (unsigned short*)(ws + 5 * padN + 32768);
    int*   esrc     = (int*)  (ws + 5 * padN + padWT);
    char*  regionA  = ws + 5 * padN + padWT + padE;              // Hpart_src, then Abf
    unsigned short* Bbf = (unsigned short*)(regionA + padAbf);   // bf16 N x 128 (row-major)
    unsigned* Hpart_dst = (unsigned*)(regionA + padAbf + padAbf);

    unsigned* Hpart_src = (unsigned*)regionA;   // dead after prep; gemm1 reuses regionA
    unsigned short* Abf = (unsigned short*)regionA;              // bf16 h

    const int NB = (N + 1023) / 1024;
    const int NW = (N + 1) >> 1;
    const int SL = ((((E + HS - 1) / HS) + 3) / 4) * 4;          // edges/slice, mult of 4

    // W transposes (tiny)
    wt_kernel<<<64, 256, 0, stream>>>(W1, W2, W1T, W2T);

    // fused src+dst histograms (packed ushort bins, zero global atomics)
    hist2_kernel<<<2 * NR_H * HS, 512, 0, stream>>>(src, dst, Hpart_src, Hpart_dst, E, SL);

    // merge src partials -> nout; prefix dst partials -> cnt_dst, nin
    prep_kernel<<<(NW + 255) / 256, 256, 0, stream>>>(Hpart_src, Hpart_dst,
                                                      cnt_dst, nout, nin, N);

    // rowstart = exclusive scan of cnt_dst
    scan_blocks_kernel<<<NB, 256, 0, stream>>>(cnt_dst, rowstart, bsum, N);
    scan_bsums_kernel<<<1, 1024, 0, stream>>>(bsum, NB);
    scan_add_kernel<<<NB, 256, 0, stream>>>(rowstart, bsum, N);

    // dst-sorted edge fill via LDS counting sort
    fillp_kernel<<<NR_F * HS, 512, 0, stream>>>(src, dst, rowstart, Hpart_dst, esrc, E, N, SL);

    const int GB = (N + 63) / 64;

    // layer 1: Abf = bf16((x*nout) @ W1) ; Bbf = bf16(relu(csr_sum(Abf)*nin + b1) * nout)
    gemm_mfma_kernel<128, false><<<GB, 256, 0, stream>>>(x, nout, W1T, Abf, N);
    agg128_kernel<<<(N * 64 + 255) / 256, 256, 0, stream>>>(
        (const __hip_bfloat162*)Abf, esrc, rowstart, cnt_dst, nin, b1, nout,
        (unsigned int*)Bbf, N);

    // layer 2: Abf = bf16(Bbf @ W2) ; out = relu(csr_sum(Abf)*nin + b2)
    gemm_mfma_kernel<64, true><<<GB, 256, 0, stream>>>(Bbf, nullptr, W2T, Abf, N);
    agg64_kernel<<<(N * 64 + 255) / 256, 256, 0, stream>>>(
        (const __hip_bfloat16*)Abf, esrc, rowstart, cnt_dst, nin, b2, out, N);
}